// Round 1
// 246.266 us; speedup vs baseline: 1.0606x; 1.0606x over previous
//
#include <hip/hip_runtime.h>
#include <hip/hip_bf16.h>

#define VNUM 6890
#define KJ 24
#define NBETA 10
#define NPOSE 207
#define KPAD 224        // NPOSE padded to 7*32
#define BATCH 1024
#define N3 20670        // VNUM*3
#define N3PAD 20672     // 323*64
#define VPAD 6912       // 108*64

// d_out element offsets (f32 elements)
#define OUT_V  0
#define OUT_JT 21166080
#define OUT_J  21239808
#define OUT_RM 21313536

// ws offsets (float units)
#define WS_JVJS 0                 // 792 floats
#define WS_ABF  792               // ushort[1024*480]  = 245760 f -> ends 246552
#define WS_WBF  246552            // ushort[6912*40]   = 138240 f -> ends 384792
#define WS_PFB  384792            // ushort[1024*224]  = 114688 f -> ends 499480
#define WS_PDT  499480            // ushort[20672*224] = 2315264 f -> ends 2814744

typedef unsigned short ushort;
typedef __attribute__((ext_vector_type(8))) short short8v;
typedef __attribute__((ext_vector_type(4))) float floatx4;

__device__ __forceinline__ ushort f2bfu(float x) {
  __hip_bfloat16 h = __float2bfloat16(x);
  union { __hip_bfloat16 h; ushort u; } cv; cv.h = h; return cv.u;
}

// ---------------------------------------------------------------------------
// Kernel 0: JvJs accumulation, split over 4 V-chunks, atomicAdd combine.
// ---------------------------------------------------------------------------
__global__ __launch_bounds__(256) void jreg_kernel(
    const float* __restrict__ Jr, const float* __restrict__ vt,
    const float* __restrict__ sd, float* __restrict__ JvJs) {
  const int j = blockIdx.x;
  const int chunk = blockIdx.y;
  const int t = threadIdx.x;
  const int lane = t & 63, wid = t >> 6;
  const int vbeg = chunk * 1723;
  const int vend = (vbeg + 1723 < VNUM) ? vbeg + 1723 : VNUM;
  __shared__ float red[4][33];
  float acc[33];
#pragma unroll
  for (int q = 0; q < 33; q++) acc[q] = 0.0f;
  for (int v = vbeg + t; v < vend; v += 256) {
    float r = Jr[j * VNUM + v];
    const float* vtp = vt + v * 3;
    const float* sdp = sd + v * 30;
    acc[0] += r * vtp[0];
    acc[1] += r * vtp[1];
    acc[2] += r * vtp[2];
#pragma unroll
    for (int q = 0; q < 30; q++) acc[3 + q] += r * sdp[q];
  }
#pragma unroll
  for (int q = 0; q < 33; q++) {
    float x = acc[q];
    for (int off = 32; off > 0; off >>= 1) x += __shfl_down(x, off, 64);
    if (lane == 0) red[wid][q] = x;
  }
  __syncthreads();
  if (t < 33)
    atomicAdd(&JvJs[j * 33 + t], red[0][t] + red[1][t] + red[2][t] + red[3][t]);
}

// ---------------------------------------------------------------------------
// Kernel 1: per-batch: rodrigues, joints_t, pose_feature(bf16), chain,
// A written directly as bf16 in MFMA-B layout: Abf[b][n(12)][k(40)], k>=24 zero.
// ---------------------------------------------------------------------------
__global__ __launch_bounds__(64) void batch_prep(
    const float* __restrict__ body_pose, const float* __restrict__ betas,
    const float* __restrict__ global_orient, const float* __restrict__ JvJs,
    float* __restrict__ out_jt, float* __restrict__ out_j, float* __restrict__ out_rm,
    ushort* __restrict__ pfb, ushort* __restrict__ Abf) {
  const int b = blockIdx.x;
  const int t = threadIdx.x;
  __shared__ float R[24][9];
  __shared__ float jt[24][3];
  __shared__ float chR[24][9];
  __shared__ float cht[24][3];

  if (t < 24) {
    float ax, ay, az;
    if (t == 0) {
      ax = global_orient[b * 3 + 0];
      ay = global_orient[b * 3 + 1];
      az = global_orient[b * 3 + 2];
    } else {
      const float* p = body_pose + (size_t)b * 69 + (t - 1) * 3;
      ax = p[0]; ay = p[1]; az = p[2];
    }
    float px = ax + 1e-8f, py = ay + 1e-8f, pz = az + 1e-8f;
    float angle = sqrtf(px * px + py * py + pz * pz);
    float inv = 1.0f / angle;
    float rx = ax * inv, ry = ay * inv, rz = az * inv;
    float s = sinf(angle), c = cosf(angle);
    float cc = 1.0f - c;
    float m[9];
    m[0] = 1.0f - cc * (ry * ry + rz * rz);
    m[1] = -s * rz + cc * rx * ry;
    m[2] =  s * ry + cc * rx * rz;
    m[3] =  s * rz + cc * rx * ry;
    m[4] = 1.0f - cc * (rx * rx + rz * rz);
    m[5] = -s * rx + cc * ry * rz;
    m[6] = -s * ry + cc * rx * rz;
    m[7] =  s * rx + cc * ry * rz;
    m[8] = 1.0f - cc * (rx * rx + ry * ry);
#pragma unroll
    for (int e = 0; e < 9; e++) {
      R[t][e] = m[e];
      out_rm[(size_t)b * 216 + t * 9 + e] = m[e];
    }
  }
  for (int idx = t; idx < 72; idx += 64) {
    int j = idx / 3, c = idx % 3;
    const float* JJ = JvJs + j * 33;
    float s = JJ[c];
    const float* be = betas + (size_t)b * NBETA;
#pragma unroll
    for (int l = 0; l < NBETA; l++) s += be[l] * JJ[3 + c * 10 + l];
    jt[j][c] = s;
    out_jt[(size_t)b * 72 + idx] = s;
  }
  __syncthreads();
  for (int mI = t; mI < KPAD; mI += 64) {
    float val = 0.0f;
    if (mI < NPOSE) {
      int k = 1 + mI / 9, e = mI % 9;
      val = R[k][e] - ((e == 0 || e == 4 || e == 8) ? 1.0f : 0.0f);
    }
    pfb[(size_t)b * KPAD + mI] = f2bfu(val);
  }
  if (t == 0) {
    const int par[24] = {-1, 0, 0, 0, 1, 2, 3, 4, 5, 6, 7, 8, 9, 9, 9, 12, 13, 14, 16, 17, 18, 19, 20, 21};
#pragma unroll
    for (int e = 0; e < 9; e++) chR[0][e] = R[0][e];
    cht[0][0] = jt[0][0]; cht[0][1] = jt[0][1]; cht[0][2] = jt[0][2];
    for (int k = 1; k < 24; k++) {
      int p = par[k];
      float rel0 = jt[k][0] - jt[p][0];
      float rel1 = jt[k][1] - jt[p][1];
      float rel2 = jt[k][2] - jt[p][2];
#pragma unroll
      for (int i = 0; i < 3; i++) {
        float a0 = chR[p][i * 3 + 0], a1 = chR[p][i * 3 + 1], a2 = chR[p][i * 3 + 2];
        chR[k][i * 3 + 0] = a0 * R[k][0] + a1 * R[k][3] + a2 * R[k][6];
        chR[k][i * 3 + 1] = a0 * R[k][1] + a1 * R[k][4] + a2 * R[k][7];
        chR[k][i * 3 + 2] = a0 * R[k][2] + a1 * R[k][5] + a2 * R[k][8];
        cht[k][i] = a0 * rel0 + a1 * rel1 + a2 * rel2 + cht[p][i];
      }
    }
  }
  __syncthreads();
  if (t < 24) {
    int k = t;
#pragma unroll
    for (int i = 0; i < 3; i++) out_j[(size_t)b * 72 + k * 3 + i] = cht[k][i];
  }
  // A in bf16, B-operand layout: Abf[b*480 + n*40 + k], n = i*4+j
  for (int e = t; e < 480; e += 64) {
    int n = e / 40, k = e - (e / 40) * 40;
    float val = 0.0f;
    if (k < 24) {
      int i = n >> 2, jj = n & 3;
      if (jj < 3) {
        val = chR[k][i * 3 + jj];
      } else {
        val = cht[k][i] - (chR[k][i * 3 + 0] * jt[k][0] +
                           chR[k][i * 3 + 1] * jt[k][1] +
                           chR[k][i * 3 + 2] * jt[k][2]);
      }
    }
    Abf[(size_t)b * 480 + e] = f2bfu(val);
  }
}

// ---------------------------------------------------------------------------
// Kernel 2: pdT[n][k] = bf16(pd[k][n]); 1080 of the 2261 blocks also convert
// lbs_weights -> bf16 padded [VPAD][40] (exactly 256 elements per block).
// ---------------------------------------------------------------------------
__global__ __launch_bounds__(256) void transpose_pd(
    const float* __restrict__ pd, ushort* __restrict__ pdT,
    const float* __restrict__ w, ushort* __restrict__ wbf) {
  {
    int lb = blockIdx.y * 323 + blockIdx.x;
    if (lb < 1080) {
      int i = lb * 256 + threadIdx.x;          // < 6912*40 = 276480 exactly
      int v = i / 40, k = i - v * 40;
      float x = (v < VNUM && k < 24) ? w[v * 24 + k] : 0.0f;
      wbf[i] = f2bfu(x);
    }
  }
  __shared__ float tile[32][65];
  const int t = threadIdx.x;
  const int n0 = blockIdx.x * 64;
  const int k0 = blockIdx.y * 32;
  const int c = t & 63;
  for (int r = t >> 6; r < 32; r += 4) {
    int k = k0 + r, n = n0 + c;
    tile[r][c] = (k < NPOSE && n < N3) ? pd[(size_t)k * N3 + n] : 0.0f;
  }
  __syncthreads();
  const int n = t >> 2;
  const int j0 = (t & 3) * 8;
  unsigned int outw[4];
#pragma unroll
  for (int jj = 0; jj < 4; jj++) {
    unsigned int lo = f2bfu(tile[j0 + jj * 2][n]);
    unsigned int hi = f2bfu(tile[j0 + jj * 2 + 1][n]);
    outw[jj] = lo | (hi << 16);
  }
  *(uint4*)&pdT[(size_t)(n0 + n) * KPAD + k0 + j0] =
      make_uint4(outw[0], outw[1], outw[2], outw[3]);
}

// ---------------------------------------------------------------------------
// Kernel 3: vposed = pf @ pd + vt + sd@betas, bf16 MFMA 16x16x32 (unchanged)
// ---------------------------------------------------------------------------
__global__ __launch_bounds__(256) void vposed_mfma(
    const ushort* __restrict__ pfb, const ushort* __restrict__ pdT,
    const float* __restrict__ vt, const float* __restrict__ sd,
    const float* __restrict__ betas, float* __restrict__ vposed) {
  __shared__ __align__(16) ushort As[64 * KPAD];
  __shared__ __align__(16) ushort Bs[64 * KPAD];
  __shared__ float vtS[64];
  __shared__ float sdS[64][10];
  __shared__ float betS[64][10];
  const int tid = threadIdx.x;
  const int lane = tid & 63, w = tid >> 6;
  const int bm = blockIdx.x * 64;
  const int bn = blockIdx.y * 64;

  {
    const uint4* srcA = (const uint4*)(pfb + (size_t)bm * KPAD);
    const uint4* srcB = (const uint4*)(pdT + (size_t)bn * KPAD);
    uint4* dA = (uint4*)As;
    uint4* dB = (uint4*)Bs;
#pragma unroll
    for (int r = 0; r < 7; r++) {
      int i = tid + r * 256;
      dA[i] = srcA[i];
      dB[i] = srcB[i];
    }
    for (int e = tid; e < 64; e += 256) {
      int gn = bn + e;
      vtS[e] = (gn < N3) ? vt[gn] : 0.0f;
    }
    for (int e = tid; e < 640; e += 256) {
      int n = e / 10, l = e % 10;
      int gn = bn + n;
      sdS[n][l] = (gn < N3) ? sd[(size_t)gn * 10 + l] : 0.0f;
      betS[n][l] = betas[(size_t)(bm + n) * 10 + l];
    }
  }
  __syncthreads();

  floatx4 acc[4];
  const floatx4 zero = {0.0f, 0.0f, 0.0f, 0.0f};
#pragma unroll
  for (int ns = 0; ns < 4; ns++) acc[ns] = zero;

  const int mrow = w * 16 + (lane & 15);
  const int quad = lane >> 4;
#pragma unroll
  for (int kb = 0; kb < 7; kb++) {
    short8v av = *(const short8v*)&As[mrow * KPAD + kb * 32 + quad * 8];
#pragma unroll
    for (int ns = 0; ns < 4; ns++) {
      short8v bv = *(const short8v*)&Bs[(ns * 16 + (lane & 15)) * KPAD + kb * 32 + quad * 8];
      acc[ns] = __builtin_amdgcn_mfma_f32_16x16x32_bf16(av, bv, acc[ns], 0, 0, 0);
    }
  }

  float betv[4][10];
#pragma unroll
  for (int reg = 0; reg < 4; reg++) {
    int ml = w * 16 + quad * 4 + reg;
#pragma unroll
    for (int l = 0; l < 10; l++) betv[reg][l] = betS[ml][l];
  }
#pragma unroll
  for (int ns = 0; ns < 4; ns++) {
    int nl = ns * 16 + (lane & 15);
    int gn = bn + nl;
    if (gn < N3) {
      float vtv = vtS[nl];
      float sdv[10];
#pragma unroll
      for (int l = 0; l < 10; l++) sdv[l] = sdS[nl][l];
#pragma unroll
      for (int reg = 0; reg < 4; reg++) {
        int ml = w * 16 + quad * 4 + reg;
        float s = acc[ns][reg] + vtv;
#pragma unroll
        for (int l = 0; l < 10; l++) s += betv[reg][l] * sdv[l];
        vposed[(size_t)(bm + ml) * N3 + gn] = s;
      }
    }
  }
}

// ---------------------------------------------------------------------------
// Kernel 4: LBS blend via MFMA, v2.
// - Ws/Bs staged via pure uint4 memcpy from pre-converted bf16 (no f2bfu,
//   no scatter -> kills the 9.2M bank-conflict cycles + staging VALU).
// - Row stride 40 ushorts (16B-unit stride 5, odd -> fragment reads uniform
//   across bank-quads).
// - T stored transposed Ts[n][v] stride 17: writes exactly 2-way (free),
//   reads 4x scalar, near conflict-free.
// - vposed loads software-pipelined 4 deep (fully unrolled so px[b&3] is
//   static-indexed), issued 4 iterations ahead of use.
// ---------------------------------------------------------------------------
__global__ __launch_bounds__(256) void blend_mfma(
    const ushort* __restrict__ wbf, const ushort* __restrict__ Abf,
    float* __restrict__ out_v) {
  __shared__ __align__(16) ushort Ws[64 * 40];          // 5 KB
  __shared__ __align__(16) ushort Bs[16 * 480 + 160];   // 15.3 KB (+zero pad)
  __shared__ float Ts[4][272];                          // per-wave, 4.25 KB
  const int tid = threadIdx.x;
  const int lane = tid & 63, wv = tid >> 6;
  const int quad = lane >> 4, l15 = lane & 15;
  const int v0 = blockIdx.x * 64;
  const int b0 = blockIdx.y * 16;

  {
    const uint4* srcW = (const uint4*)(wbf + (size_t)v0 * 40);
    uint4* dstW = (uint4*)Ws;
    dstW[tid] = srcW[tid];
    if (tid < 64) dstW[256 + tid] = srcW[256 + tid];
    const uint4* srcB = (const uint4*)(Abf + (size_t)b0 * 480);
    uint4* dstB = (uint4*)Bs;
#pragma unroll
    for (int r = 0; r < 3; r++) dstB[tid + r * 256] = srcB[tid + r * 256];
    if (tid < 192) dstB[768 + tid] = srcB[768 + tid];
    if (tid < 20) dstB[960 + tid] = make_uint4(0u, 0u, 0u, 0u);
  }
  __syncthreads();

  const short8v af = *(const short8v*)&Ws[(wv * 16 + l15) * 40 + quad * 8];

  // apply-phase lane mapping: lanes 0..47 -> (vertex, component)
  const int al = (lane < 48) ? lane : 0;
  const int appv = al / 3;
  const int appc = al - appv * 3;
  const int gv = v0 + wv * 16 + appv;
  const bool active = (lane < 48) && (gv < VNUM);
  float* myTs = &Ts[wv][0];
  const size_t vbase = (size_t)gv * 3;

  float px[4], py[4], pz[4];
#pragma unroll
  for (int i = 0; i < 4; i++) {
    if (active) {
      const float* p = out_v + (size_t)(b0 + i) * N3 + vbase;
      px[i] = p[0]; py[i] = p[1]; pz[i] = p[2];
    }
  }

#pragma unroll
  for (int b = 0; b < 16; b++) {
    const int slot = b & 3;   // compile-time after full unroll
    short8v bf = *(const short8v*)&Bs[b * 480 + l15 * 40 + quad * 8];
    floatx4 acc = {0.0f, 0.0f, 0.0f, 0.0f};
    acc = __builtin_amdgcn_mfma_f32_16x16x32_bf16(af, bf, acc, 0, 0, 0);
    // C: lane holds T[v'=quad*4+r][n=l15]; store transposed Ts[n][v'] (stride 17)
#pragma unroll
    for (int r = 0; r < 4; r++) myTs[l15 * 17 + quad * 4 + r] = acc[r];
    __builtin_amdgcn_sched_barrier(0);
    __builtin_amdgcn_s_waitcnt(0xc07f);   // lgkmcnt(0): wave's T writes done
    __builtin_amdgcn_sched_barrier(0);
    float t0 = myTs[(appc * 4 + 0) * 17 + appv];
    float t1 = myTs[(appc * 4 + 1) * 17 + appv];
    float t2 = myTs[(appc * 4 + 2) * 17 + appv];
    float t3 = myTs[(appc * 4 + 3) * 17 + appv];
    if (active) {
      out_v[(size_t)(b0 + b) * N3 + vbase + appc] =
          t0 * px[slot] + t1 * py[slot] + t2 * pz[slot] + t3;
      if (b < 12) {
        const float* p = out_v + (size_t)(b0 + b + 4) * N3 + vbase;
        px[slot] = p[0]; py[slot] = p[1]; pz[slot] = p[2];
      }
    }
  }
}

extern "C" void kernel_launch(void* const* d_in, const int* in_sizes, int n_in,
                              void* d_out, int out_size, void* d_ws, size_t ws_size,
                              hipStream_t stream) {
  const float* body_pose     = (const float*)d_in[0];
  const float* betas         = (const float*)d_in[1];
  const float* global_orient = (const float*)d_in[2];
  const float* v_template    = (const float*)d_in[3];
  const float* shapedirs     = (const float*)d_in[4];
  const float* posedirs      = (const float*)d_in[5];
  const float* J_regressor   = (const float*)d_in[6];
  const float* lbs_weights   = (const float*)d_in[7];

  float* out = (float*)d_out;
  float* out_v  = out + OUT_V;
  float* out_jt = out + OUT_JT;
  float* out_j  = out + OUT_J;
  float* out_rm = out + OUT_RM;

  float* ws = (float*)d_ws;
  float* JvJs = ws + WS_JVJS;
  ushort* Abf = (ushort*)(ws + WS_ABF);
  ushort* wbf = (ushort*)(ws + WS_WBF);
  ushort* pfb = (ushort*)(ws + WS_PFB);
  ushort* pdT = (ushort*)(ws + WS_PDT);

  hipMemsetAsync(JvJs, 0, KJ * 33 * sizeof(float), stream);
  jreg_kernel<<<dim3(KJ, 4), 256, 0, stream>>>(J_regressor, v_template, shapedirs, JvJs);
  transpose_pd<<<dim3(323, 7), 256, 0, stream>>>(posedirs, pdT, lbs_weights, wbf);
  batch_prep<<<BATCH, 64, 0, stream>>>(body_pose, betas, global_orient, JvJs,
                                       out_jt, out_j, out_rm, pfb, Abf);
  vposed_mfma<<<dim3(16, 323), 256, 0, stream>>>(pfb, pdT, v_template,
                                                 shapedirs, betas, out_v);
  blend_mfma<<<dim3(108, 64), 256, 0, stream>>>(wbf, Abf, out_v);
}

// Round 2
// 230.793 us; speedup vs baseline: 1.1317x; 1.0670x over previous
//
#include <hip/hip_runtime.h>
#include <hip/hip_bf16.h>

#define VNUM 6890
#define KJ 24
#define NBETA 10
#define NPOSE 207
#define KPAD 224        // NPOSE padded to 7*32
#define BATCH 1024
#define N3 20670        // VNUM*3
#define N3PAD 20672     // 323*64
#define VPAD 6912       // 108*64

// d_out element offsets (f32 elements)
#define OUT_V  0
#define OUT_JT 21166080
#define OUT_J  21239808
#define OUT_RM 21313536

// ws offsets (float units)
#define WS_JVJS 0                 // 792 floats
#define WS_ABF  792               // ushort[1024*480]  = 245760 f -> ends 246552
#define WS_WBF  246552            // ushort[6912*40]   = 138240 f -> ends 384792
#define WS_PFB  384792            // ushort[1024*224]  = 114688 f -> ends 499480
#define WS_PDT  499480            // ushort[20672*224] = 2315264 f -> ends 2814744

typedef unsigned short ushort;
typedef __attribute__((ext_vector_type(8))) short short8v;
typedef __attribute__((ext_vector_type(4))) float floatx4;

__device__ __forceinline__ ushort f2bfu(float x) {
  __hip_bfloat16 h = __float2bfloat16(x);
  union { __hip_bfloat16 h; ushort u; } cv; cv.h = h; return cv.u;
}

// ---------------------------------------------------------------------------
// Kernel 0: JvJs accumulation, split over 4 V-chunks, atomicAdd combine.
// ---------------------------------------------------------------------------
__global__ __launch_bounds__(256) void jreg_kernel(
    const float* __restrict__ Jr, const float* __restrict__ vt,
    const float* __restrict__ sd, float* __restrict__ JvJs) {
  const int j = blockIdx.x;
  const int chunk = blockIdx.y;
  const int t = threadIdx.x;
  const int lane = t & 63, wid = t >> 6;
  const int vbeg = chunk * 1723;
  const int vend = (vbeg + 1723 < VNUM) ? vbeg + 1723 : VNUM;
  __shared__ float red[4][33];
  float acc[33];
#pragma unroll
  for (int q = 0; q < 33; q++) acc[q] = 0.0f;
  for (int v = vbeg + t; v < vend; v += 256) {
    float r = Jr[j * VNUM + v];
    const float* vtp = vt + v * 3;
    const float* sdp = sd + v * 30;
    acc[0] += r * vtp[0];
    acc[1] += r * vtp[1];
    acc[2] += r * vtp[2];
#pragma unroll
    for (int q = 0; q < 30; q++) acc[3 + q] += r * sdp[q];
  }
#pragma unroll
  for (int q = 0; q < 33; q++) {
    float x = acc[q];
    for (int off = 32; off > 0; off >>= 1) x += __shfl_down(x, off, 64);
    if (lane == 0) red[wid][q] = x;
  }
  __syncthreads();
  if (t < 33)
    atomicAdd(&JvJs[j * 33 + t], red[0][t] + red[1][t] + red[2][t] + red[3][t]);
}

// ---------------------------------------------------------------------------
// Kernel 1: per-batch: rodrigues, joints_t, pose_feature(bf16), chain,
// A written directly as bf16 in MFMA layout: Abf[b][n(12)][k(40)], k>=24 zero.
// ---------------------------------------------------------------------------
__global__ __launch_bounds__(64) void batch_prep(
    const float* __restrict__ body_pose, const float* __restrict__ betas,
    const float* __restrict__ global_orient, const float* __restrict__ JvJs,
    float* __restrict__ out_jt, float* __restrict__ out_j, float* __restrict__ out_rm,
    ushort* __restrict__ pfb, ushort* __restrict__ Abf) {
  const int b = blockIdx.x;
  const int t = threadIdx.x;
  __shared__ float R[24][9];
  __shared__ float jt[24][3];
  __shared__ float chR[24][9];
  __shared__ float cht[24][3];

  if (t < 24) {
    float ax, ay, az;
    if (t == 0) {
      ax = global_orient[b * 3 + 0];
      ay = global_orient[b * 3 + 1];
      az = global_orient[b * 3 + 2];
    } else {
      const float* p = body_pose + (size_t)b * 69 + (t - 1) * 3;
      ax = p[0]; ay = p[1]; az = p[2];
    }
    float px = ax + 1e-8f, py = ay + 1e-8f, pz = az + 1e-8f;
    float angle = sqrtf(px * px + py * py + pz * pz);
    float inv = 1.0f / angle;
    float rx = ax * inv, ry = ay * inv, rz = az * inv;
    float s = sinf(angle), c = cosf(angle);
    float cc = 1.0f - c;
    float m[9];
    m[0] = 1.0f - cc * (ry * ry + rz * rz);
    m[1] = -s * rz + cc * rx * ry;
    m[2] =  s * ry + cc * rx * rz;
    m[3] =  s * rz + cc * rx * ry;
    m[4] = 1.0f - cc * (rx * rx + rz * rz);
    m[5] = -s * rx + cc * ry * rz;
    m[6] = -s * ry + cc * rx * rz;
    m[7] =  s * rx + cc * ry * rz;
    m[8] = 1.0f - cc * (rx * rx + ry * ry);
#pragma unroll
    for (int e = 0; e < 9; e++) {
      R[t][e] = m[e];
      out_rm[(size_t)b * 216 + t * 9 + e] = m[e];
    }
  }
  for (int idx = t; idx < 72; idx += 64) {
    int j = idx / 3, c = idx % 3;
    const float* JJ = JvJs + j * 33;
    float s = JJ[c];
    const float* be = betas + (size_t)b * NBETA;
#pragma unroll
    for (int l = 0; l < NBETA; l++) s += be[l] * JJ[3 + c * 10 + l];
    jt[j][c] = s;
    out_jt[(size_t)b * 72 + idx] = s;
  }
  __syncthreads();
  for (int mI = t; mI < KPAD; mI += 64) {
    float val = 0.0f;
    if (mI < NPOSE) {
      int k = 1 + mI / 9, e = mI % 9;
      val = R[k][e] - ((e == 0 || e == 4 || e == 8) ? 1.0f : 0.0f);
    }
    pfb[(size_t)b * KPAD + mI] = f2bfu(val);
  }
  if (t == 0) {
    const int par[24] = {-1, 0, 0, 0, 1, 2, 3, 4, 5, 6, 7, 8, 9, 9, 9, 12, 13, 14, 16, 17, 18, 19, 20, 21};
#pragma unroll
    for (int e = 0; e < 9; e++) chR[0][e] = R[0][e];
    cht[0][0] = jt[0][0]; cht[0][1] = jt[0][1]; cht[0][2] = jt[0][2];
    for (int k = 1; k < 24; k++) {
      int p = par[k];
      float rel0 = jt[k][0] - jt[p][0];
      float rel1 = jt[k][1] - jt[p][1];
      float rel2 = jt[k][2] - jt[p][2];
#pragma unroll
      for (int i = 0; i < 3; i++) {
        float a0 = chR[p][i * 3 + 0], a1 = chR[p][i * 3 + 1], a2 = chR[p][i * 3 + 2];
        chR[k][i * 3 + 0] = a0 * R[k][0] + a1 * R[k][3] + a2 * R[k][6];
        chR[k][i * 3 + 1] = a0 * R[k][1] + a1 * R[k][4] + a2 * R[k][7];
        chR[k][i * 3 + 2] = a0 * R[k][2] + a1 * R[k][5] + a2 * R[k][8];
        cht[k][i] = a0 * rel0 + a1 * rel1 + a2 * rel2 + cht[p][i];
      }
    }
  }
  __syncthreads();
  if (t < 24) {
    int k = t;
#pragma unroll
    for (int i = 0; i < 3; i++) out_j[(size_t)b * 72 + k * 3 + i] = cht[k][i];
  }
  // A in bf16, layout: Abf[b*480 + n*40 + k], n = i*4+j
  for (int e = t; e < 480; e += 64) {
    int n = e / 40, k = e - (e / 40) * 40;
    float val = 0.0f;
    if (k < 24) {
      int i = n >> 2, jj = n & 3;
      if (jj < 3) {
        val = chR[k][i * 3 + jj];
      } else {
        val = cht[k][i] - (chR[k][i * 3 + 0] * jt[k][0] +
                           chR[k][i * 3 + 1] * jt[k][1] +
                           chR[k][i * 3 + 2] * jt[k][2]);
      }
    }
    Abf[(size_t)b * 480 + e] = f2bfu(val);
  }
}

// ---------------------------------------------------------------------------
// Kernel 2: pdT[n][k] = bf16(pd[k][n]); 1080 of the 2261 blocks also convert
// lbs_weights -> bf16 padded [VPAD][40] (exactly 256 elements per block).
// ---------------------------------------------------------------------------
__global__ __launch_bounds__(256) void transpose_pd(
    const float* __restrict__ pd, ushort* __restrict__ pdT,
    const float* __restrict__ w, ushort* __restrict__ wbf) {
  {
    int lb = blockIdx.y * 323 + blockIdx.x;
    if (lb < 1080) {
      int i = lb * 256 + threadIdx.x;          // < 6912*40 = 276480 exactly
      int v = i / 40, k = i - v * 40;
      float x = (v < VNUM && k < 24) ? w[v * 24 + k] : 0.0f;
      wbf[i] = f2bfu(x);
    }
  }
  __shared__ float tile[32][65];
  const int t = threadIdx.x;
  const int n0 = blockIdx.x * 64;
  const int k0 = blockIdx.y * 32;
  const int c = t & 63;
  for (int r = t >> 6; r < 32; r += 4) {
    int k = k0 + r, n = n0 + c;
    tile[r][c] = (k < NPOSE && n < N3) ? pd[(size_t)k * N3 + n] : 0.0f;
  }
  __syncthreads();
  const int n = t >> 2;
  const int j0 = (t & 3) * 8;
  unsigned int outw[4];
#pragma unroll
  for (int jj = 0; jj < 4; jj++) {
    unsigned int lo = f2bfu(tile[j0 + jj * 2][n]);
    unsigned int hi = f2bfu(tile[j0 + jj * 2 + 1][n]);
    outw[jj] = lo | (hi << 16);
  }
  *(uint4*)&pdT[(size_t)(n0 + n) * KPAD + k0 + j0] =
      make_uint4(outw[0], outw[1], outw[2], outw[3]);
}

// ---------------------------------------------------------------------------
// Kernel 3: vposed = pf @ pd + vt + sd@betas, bf16 MFMA 16x16x32 (unchanged)
// ---------------------------------------------------------------------------
__global__ __launch_bounds__(256) void vposed_mfma(
    const ushort* __restrict__ pfb, const ushort* __restrict__ pdT,
    const float* __restrict__ vt, const float* __restrict__ sd,
    const float* __restrict__ betas, float* __restrict__ vposed) {
  __shared__ __align__(16) ushort As[64 * KPAD];
  __shared__ __align__(16) ushort Bs[64 * KPAD];
  __shared__ float vtS[64];
  __shared__ float sdS[64][10];
  __shared__ float betS[64][10];
  const int tid = threadIdx.x;
  const int lane = tid & 63, w = tid >> 6;
  const int bm = blockIdx.x * 64;
  const int bn = blockIdx.y * 64;

  {
    const uint4* srcA = (const uint4*)(pfb + (size_t)bm * KPAD);
    const uint4* srcB = (const uint4*)(pdT + (size_t)bn * KPAD);
    uint4* dA = (uint4*)As;
    uint4* dB = (uint4*)Bs;
#pragma unroll
    for (int r = 0; r < 7; r++) {
      int i = tid + r * 256;
      dA[i] = srcA[i];
      dB[i] = srcB[i];
    }
    for (int e = tid; e < 64; e += 256) {
      int gn = bn + e;
      vtS[e] = (gn < N3) ? vt[gn] : 0.0f;
    }
    for (int e = tid; e < 640; e += 256) {
      int n = e / 10, l = e % 10;
      int gn = bn + n;
      sdS[n][l] = (gn < N3) ? sd[(size_t)gn * 10 + l] : 0.0f;
      betS[n][l] = betas[(size_t)(bm + n) * 10 + l];
    }
  }
  __syncthreads();

  floatx4 acc[4];
  const floatx4 zero = {0.0f, 0.0f, 0.0f, 0.0f};
#pragma unroll
  for (int ns = 0; ns < 4; ns++) acc[ns] = zero;

  const int mrow = w * 16 + (lane & 15);
  const int quad = lane >> 4;
#pragma unroll
  for (int kb = 0; kb < 7; kb++) {
    short8v av = *(const short8v*)&As[mrow * KPAD + kb * 32 + quad * 8];
#pragma unroll
    for (int ns = 0; ns < 4; ns++) {
      short8v bv = *(const short8v*)&Bs[(ns * 16 + (lane & 15)) * KPAD + kb * 32 + quad * 8];
      acc[ns] = __builtin_amdgcn_mfma_f32_16x16x32_bf16(av, bv, acc[ns], 0, 0, 0);
    }
  }

  float betv[4][10];
#pragma unroll
  for (int reg = 0; reg < 4; reg++) {
    int ml = w * 16 + quad * 4 + reg;
#pragma unroll
    for (int l = 0; l < 10; l++) betv[reg][l] = betS[ml][l];
  }
#pragma unroll
  for (int ns = 0; ns < 4; ns++) {
    int nl = ns * 16 + (lane & 15);
    int gn = bn + nl;
    if (gn < N3) {
      float vtv = vtS[nl];
      float sdv[10];
#pragma unroll
      for (int l = 0; l < 10; l++) sdv[l] = sdS[nl][l];
#pragma unroll
      for (int reg = 0; reg < 4; reg++) {
        int ml = w * 16 + quad * 4 + reg;
        float s = acc[ns][reg] + vtv;
#pragma unroll
        for (int l = 0; l < 10; l++) s += betv[reg][l] * sdv[l];
        vposed[(size_t)(bm + ml) * N3 + gn] = s;
      }
    }
  }
}

// ---------------------------------------------------------------------------
// Kernel 4: LBS blend via MFMA, v3 — transposed MFMA, zero LDS round-trip.
// Compute T^T = mfma(Abf_frag, W_frag): lane (quad,l15) holds
// D[n=4*quad+r][v=l15] = T[v=l15][4*quad+r]. For quad<3 that is exactly
// (Rx,Ry,Rz,t) for vertex l15, component c=quad -> apply directly from AGPRs.
// No Ts buffer, no lgkmcnt walls, 1 LDS instr per iter (was 9).
// A-operand rows l15>=12 read the zero/next-batch pad (in-bounds) and land
// only in quad==3 lanes, which never store.
// ---------------------------------------------------------------------------
__global__ __launch_bounds__(256) void blend_mfma(
    const ushort* __restrict__ wbf, const ushort* __restrict__ Abf,
    float* __restrict__ out_v) {
  __shared__ __align__(16) ushort Ws[64 * 40];          // 5 KB
  __shared__ __align__(16) ushort Bs[16 * 480 + 160];   // 15.3 KB (+pad)
  const int tid = threadIdx.x;
  const int lane = tid & 63, wv = tid >> 6;
  const int quad = lane >> 4, l15 = lane & 15;
  const int v0 = blockIdx.x * 64;
  const int b0 = blockIdx.y * 16;

  {
    const uint4* srcW = (const uint4*)(wbf + (size_t)v0 * 40);
    uint4* dstW = (uint4*)Ws;
    dstW[tid] = srcW[tid];
    if (tid < 64) dstW[256 + tid] = srcW[256 + tid];
    const uint4* srcB = (const uint4*)(Abf + (size_t)b0 * 480);
    uint4* dstB = (uint4*)Bs;
#pragma unroll
    for (int r = 0; r < 3; r++) dstB[tid + r * 256] = srcB[tid + r * 256];
    if (tid < 192) dstB[768 + tid] = srcB[768 + tid];
    if (tid < 20) dstB[960 + tid] = make_uint4(0u, 0u, 0u, 0u);
  }
  __syncthreads();

  // B-operand: W fragment, col = l15 -> vertex wv*16+l15, k = quad*8..+7
  const short8v wf = *(const short8v*)&Ws[(wv * 16 + l15) * 40 + quad * 8];

  const int gv = v0 + wv * 16 + l15;
  const bool active = (quad < 3) && (gv < VNUM);
  const size_t vbase = (size_t)gv * 3;

  float px[4], py[4], pz[4];
#pragma unroll
  for (int i = 0; i < 4; i++) {
    if (active) {
      const float* p = out_v + (size_t)(b0 + i) * N3 + vbase;
      px[i] = p[0]; py[i] = p[1]; pz[i] = p[2];
    }
  }

#pragma unroll
  for (int b = 0; b < 16; b++) {
    const int slot = b & 3;   // compile-time after full unroll
    // A-operand: Abf fragment, row = l15 (n), k = quad*8..+7
    short8v afrag = *(const short8v*)&Bs[b * 480 + l15 * 40 + quad * 8];
    floatx4 acc = {0.0f, 0.0f, 0.0f, 0.0f};
    acc = __builtin_amdgcn_mfma_f32_16x16x32_bf16(afrag, wf, acc, 0, 0, 0);
    if (active) {
      out_v[(size_t)(b0 + b) * N3 + vbase + quad] =
          acc[0] * px[slot] + acc[1] * py[slot] + acc[2] * pz[slot] + acc[3];
      if (b < 12) {
        const float* p = out_v + (size_t)(b0 + b + 4) * N3 + vbase;
        px[slot] = p[0]; py[slot] = p[1]; pz[slot] = p[2];
      }
    }
  }
}

extern "C" void kernel_launch(void* const* d_in, const int* in_sizes, int n_in,
                              void* d_out, int out_size, void* d_ws, size_t ws_size,
                              hipStream_t stream) {
  const float* body_pose     = (const float*)d_in[0];
  const float* betas         = (const float*)d_in[1];
  const float* global_orient = (const float*)d_in[2];
  const float* v_template    = (const float*)d_in[3];
  const float* shapedirs     = (const float*)d_in[4];
  const float* posedirs      = (const float*)d_in[5];
  const float* J_regressor   = (const float*)d_in[6];
  const float* lbs_weights   = (const float*)d_in[7];

  float* out = (float*)d_out;
  float* out_v  = out + OUT_V;
  float* out_jt = out + OUT_JT;
  float* out_j  = out + OUT_J;
  float* out_rm = out + OUT_RM;

  float* ws = (float*)d_ws;
  float* JvJs = ws + WS_JVJS;
  ushort* Abf = (ushort*)(ws + WS_ABF);
  ushort* wbf = (ushort*)(ws + WS_WBF);
  ushort* pfb = (ushort*)(ws + WS_PFB);
  ushort* pdT = (ushort*)(ws + WS_PDT);

  hipMemsetAsync(JvJs, 0, KJ * 33 * sizeof(float), stream);
  jreg_kernel<<<dim3(KJ, 4), 256, 0, stream>>>(J_regressor, v_template, shapedirs, JvJs);
  transpose_pd<<<dim3(323, 7), 256, 0, stream>>>(posedirs, pdT, lbs_weights, wbf);
  batch_prep<<<BATCH, 64, 0, stream>>>(body_pose, betas, global_orient, JvJs,
                                       out_jt, out_j, out_rm, pfb, Abf);
  vposed_mfma<<<dim3(16, 323), 256, 0, stream>>>(pfb, pdT, v_template,
                                                 shapedirs, betas, out_v);
  blend_mfma<<<dim3(108, 64), 256, 0, stream>>>(wbf, Abf, out_v);
}

// Round 3
// 212.581 us; speedup vs baseline: 1.2286x; 1.0857x over previous
//
#include <hip/hip_runtime.h>
#include <hip/hip_bf16.h>

#define VNUM 6890
#define KJ 24
#define NBETA 10
#define NPOSE 207
#define KPAD 224        // NPOSE padded to 7*32; cols 207..216 carry betas/sd
#define BATCH 1024
#define N3 20670        // VNUM*3
#define N3PAD 20672     // 323*64
#define VPAD 6912       // 108*64

// d_out element offsets (f32 elements)
#define OUT_V  0
#define OUT_JT 21166080
#define OUT_J  21239808
#define OUT_RM 21313536

// ws offsets (float units)
#define WS_JVJS 0                 // 792 floats
#define WS_ABF  792               // ushort[1024*480]  = 245760 f -> ends 246552
#define WS_WBF  246552            // ushort[6912*40]   = 138240 f -> ends 384792
#define WS_PFB  384792            // ushort[1024*224]  = 114688 f -> ends 499480
#define WS_PDT  499480            // ushort[20672*224] = 2315264 f -> ends 2814744

typedef unsigned short ushort;
typedef __attribute__((ext_vector_type(8))) short short8v;
typedef __attribute__((ext_vector_type(4))) float floatx4;

__device__ __forceinline__ ushort f2bfu(float x) {
  __hip_bfloat16 h = __float2bfloat16(x);
  union { __hip_bfloat16 h; ushort u; } cv; cv.h = h; return cv.u;
}

// ---------------------------------------------------------------------------
// Kernel 0: JvJs accumulation, split over 4 V-chunks, atomicAdd combine.
// ---------------------------------------------------------------------------
__global__ __launch_bounds__(256) void jreg_kernel(
    const float* __restrict__ Jr, const float* __restrict__ vt,
    const float* __restrict__ sd, float* __restrict__ JvJs) {
  const int j = blockIdx.x;
  const int chunk = blockIdx.y;
  const int t = threadIdx.x;
  const int lane = t & 63, wid = t >> 6;
  const int vbeg = chunk * 1723;
  const int vend = (vbeg + 1723 < VNUM) ? vbeg + 1723 : VNUM;
  __shared__ float red[4][33];
  float acc[33];
#pragma unroll
  for (int q = 0; q < 33; q++) acc[q] = 0.0f;
  for (int v = vbeg + t; v < vend; v += 256) {
    float r = Jr[j * VNUM + v];
    const float* vtp = vt + v * 3;
    const float* sdp = sd + v * 30;
    acc[0] += r * vtp[0];
    acc[1] += r * vtp[1];
    acc[2] += r * vtp[2];
#pragma unroll
    for (int q = 0; q < 30; q++) acc[3 + q] += r * sdp[q];
  }
#pragma unroll
  for (int q = 0; q < 33; q++) {
    float x = acc[q];
    for (int off = 32; off > 0; off >>= 1) x += __shfl_down(x, off, 64);
    if (lane == 0) red[wid][q] = x;
  }
  __syncthreads();
  if (t < 33)
    atomicAdd(&JvJs[j * 33 + t], red[0][t] + red[1][t] + red[2][t] + red[3][t]);
}

// ---------------------------------------------------------------------------
// Kernel 1: per-batch: rodrigues, joints_t, pose_feature+betas (bf16), chain,
// A written directly as bf16 in MFMA layout: Abf[b][n(12)][k(40)], k>=24 zero.
// pfb row layout: [0..206]=pose_feature, [207..216]=betas, [217..223]=0.
// ---------------------------------------------------------------------------
__global__ __launch_bounds__(64) void batch_prep(
    const float* __restrict__ body_pose, const float* __restrict__ betas,
    const float* __restrict__ global_orient, const float* __restrict__ JvJs,
    float* __restrict__ out_jt, float* __restrict__ out_j, float* __restrict__ out_rm,
    ushort* __restrict__ pfb, ushort* __restrict__ Abf) {
  const int b = blockIdx.x;
  const int t = threadIdx.x;
  __shared__ float R[24][9];
  __shared__ float jt[24][3];
  __shared__ float chR[24][9];
  __shared__ float cht[24][3];

  if (t < 24) {
    float ax, ay, az;
    if (t == 0) {
      ax = global_orient[b * 3 + 0];
      ay = global_orient[b * 3 + 1];
      az = global_orient[b * 3 + 2];
    } else {
      const float* p = body_pose + (size_t)b * 69 + (t - 1) * 3;
      ax = p[0]; ay = p[1]; az = p[2];
    }
    float px = ax + 1e-8f, py = ay + 1e-8f, pz = az + 1e-8f;
    float angle = sqrtf(px * px + py * py + pz * pz);
    float inv = 1.0f / angle;
    float rx = ax * inv, ry = ay * inv, rz = az * inv;
    float s = sinf(angle), c = cosf(angle);
    float cc = 1.0f - c;
    float m[9];
    m[0] = 1.0f - cc * (ry * ry + rz * rz);
    m[1] = -s * rz + cc * rx * ry;
    m[2] =  s * ry + cc * rx * rz;
    m[3] =  s * rz + cc * rx * ry;
    m[4] = 1.0f - cc * (rx * rx + rz * rz);
    m[5] = -s * rx + cc * ry * rz;
    m[6] = -s * ry + cc * rx * rz;
    m[7] =  s * rx + cc * ry * rz;
    m[8] = 1.0f - cc * (rx * rx + ry * ry);
#pragma unroll
    for (int e = 0; e < 9; e++) {
      R[t][e] = m[e];
      out_rm[(size_t)b * 216 + t * 9 + e] = m[e];
    }
  }
  for (int idx = t; idx < 72; idx += 64) {
    int j = idx / 3, c = idx % 3;
    const float* JJ = JvJs + j * 33;
    float s = JJ[c];
    const float* be = betas + (size_t)b * NBETA;
#pragma unroll
    for (int l = 0; l < NBETA; l++) s += be[l] * JJ[3 + c * 10 + l];
    jt[j][c] = s;
    out_jt[(size_t)b * 72 + idx] = s;
  }
  __syncthreads();
  for (int mI = t; mI < KPAD; mI += 64) {
    float val = 0.0f;
    if (mI < NPOSE) {
      int k = 1 + mI / 9, e = mI % 9;
      val = R[k][e] - ((e == 0 || e == 4 || e == 8) ? 1.0f : 0.0f);
    } else if (mI < NPOSE + NBETA) {
      val = betas[(size_t)b * NBETA + (mI - NPOSE)];
    }
    pfb[(size_t)b * KPAD + mI] = f2bfu(val);
  }
  if (t == 0) {
    const int par[24] = {-1, 0, 0, 0, 1, 2, 3, 4, 5, 6, 7, 8, 9, 9, 9, 12, 13, 14, 16, 17, 18, 19, 20, 21};
#pragma unroll
    for (int e = 0; e < 9; e++) chR[0][e] = R[0][e];
    cht[0][0] = jt[0][0]; cht[0][1] = jt[0][1]; cht[0][2] = jt[0][2];
    for (int k = 1; k < 24; k++) {
      int p = par[k];
      float rel0 = jt[k][0] - jt[p][0];
      float rel1 = jt[k][1] - jt[p][1];
      float rel2 = jt[k][2] - jt[p][2];
#pragma unroll
      for (int i = 0; i < 3; i++) {
        float a0 = chR[p][i * 3 + 0], a1 = chR[p][i * 3 + 1], a2 = chR[p][i * 3 + 2];
        chR[k][i * 3 + 0] = a0 * R[k][0] + a1 * R[k][3] + a2 * R[k][6];
        chR[k][i * 3 + 1] = a0 * R[k][1] + a1 * R[k][4] + a2 * R[k][7];
        chR[k][i * 3 + 2] = a0 * R[k][2] + a1 * R[k][5] + a2 * R[k][8];
        cht[k][i] = a0 * rel0 + a1 * rel1 + a2 * rel2 + cht[p][i];
      }
    }
  }
  __syncthreads();
  if (t < 24) {
    int k = t;
#pragma unroll
    for (int i = 0; i < 3; i++) out_j[(size_t)b * 72 + k * 3 + i] = cht[k][i];
  }
  // A in bf16, layout: Abf[b*480 + n*40 + k], n = i*4+j
  for (int e = t; e < 480; e += 64) {
    int n = e / 40, k = e - (e / 40) * 40;
    float val = 0.0f;
    if (k < 24) {
      int i = n >> 2, jj = n & 3;
      if (jj < 3) {
        val = chR[k][i * 3 + jj];
      } else {
        val = cht[k][i] - (chR[k][i * 3 + 0] * jt[k][0] +
                           chR[k][i * 3 + 1] * jt[k][1] +
                           chR[k][i * 3 + 2] * jt[k][2]);
      }
    }
    Abf[(size_t)b * 480 + e] = f2bfu(val);
  }
}

// ---------------------------------------------------------------------------
// Kernel 2: pdT[n][k] = bf16(pd[k][n]) for k<207; k in 207..216 = sd[n][k-207];
// k>=217 zero. 1080 of the 2261 blocks also convert lbs_weights -> bf16 [VPAD][40].
// ---------------------------------------------------------------------------
__global__ __launch_bounds__(256) void transpose_pd(
    const float* __restrict__ pd, ushort* __restrict__ pdT,
    const float* __restrict__ sd,
    const float* __restrict__ w, ushort* __restrict__ wbf) {
  {
    int lb = blockIdx.y * 323 + blockIdx.x;
    if (lb < 1080) {
      int i = lb * 256 + threadIdx.x;          // < 6912*40 = 276480 exactly
      int v = i / 40, k = i - v * 40;
      float x = (v < VNUM && k < 24) ? w[v * 24 + k] : 0.0f;
      wbf[i] = f2bfu(x);
    }
  }
  __shared__ float tile[32][65];
  const int t = threadIdx.x;
  const int n0 = blockIdx.x * 64;
  const int k0 = blockIdx.y * 32;
  const int c = t & 63;
  for (int r = t >> 6; r < 32; r += 4) {
    int k = k0 + r, n = n0 + c;
    float x = 0.0f;
    if (n < N3) {
      if (k < NPOSE) x = pd[(size_t)k * N3 + n];
      else if (k < NPOSE + NBETA) x = sd[(size_t)n * 10 + (k - NPOSE)];
    }
    tile[r][c] = x;
  }
  __syncthreads();
  const int n = t >> 2;
  const int j0 = (t & 3) * 8;
  unsigned int outw[4];
#pragma unroll
  for (int jj = 0; jj < 4; jj++) {
    unsigned int lo = f2bfu(tile[j0 + jj * 2][n]);
    unsigned int hi = f2bfu(tile[j0 + jj * 2 + 1][n]);
    outw[jj] = lo | (hi << 16);
  }
  *(uint4*)&pdT[(size_t)(n0 + n) * KPAD + k0 + j0] =
      make_uint4(outw[0], outw[1], outw[2], outw[3]);
}

// ---------------------------------------------------------------------------
// Kernel 3: vposed = pf_ext @ pdT_ext + vt   (sd@betas folded into K=217)
// A-fragments loaded straight from global (pfb is L2-resident, 323x reuse);
// only B tile in LDS -> 29 KB -> 5 blocks/CU (was 2).
// ---------------------------------------------------------------------------
__global__ __launch_bounds__(256, 5) void vposed_mfma(
    const ushort* __restrict__ pfb, const ushort* __restrict__ pdT,
    const float* __restrict__ vt, float* __restrict__ vposed) {
  __shared__ __align__(16) ushort Bs[64 * KPAD];   // 28 KB
  __shared__ float vtS[64];
  const int tid = threadIdx.x;
  const int lane = tid & 63, w = tid >> 6;
  const int l15 = lane & 15, quad = lane >> 4;
  const int bm = blockIdx.x * 64;
  const int bn = blockIdx.y * 64;
  const int mrow = w * 16 + l15;

  // A-fragments direct from global (issued first; latency hides under staging)
  short8v av[7];
  const ushort* arow = pfb + (size_t)(bm + mrow) * KPAD;
#pragma unroll
  for (int kb = 0; kb < 7; kb++)
    av[kb] = *(const short8v*)(arow + kb * 32 + quad * 8);

  {
    const uint4* srcB = (const uint4*)(pdT + (size_t)bn * KPAD);
    uint4* dB = (uint4*)Bs;
#pragma unroll
    for (int r = 0; r < 7; r++) dB[tid + r * 256] = srcB[tid + r * 256];
    if (tid < 64) vtS[tid] = (bn + tid < N3) ? vt[bn + tid] : 0.0f;
  }
  __syncthreads();

  floatx4 acc[4];
  const floatx4 zero = {0.0f, 0.0f, 0.0f, 0.0f};
#pragma unroll
  for (int ns = 0; ns < 4; ns++) acc[ns] = zero;

#pragma unroll
  for (int kb = 0; kb < 7; kb++) {
#pragma unroll
    for (int ns = 0; ns < 4; ns++) {
      short8v bv = *(const short8v*)&Bs[(ns * 16 + l15) * KPAD + kb * 32 + quad * 8];
      acc[ns] = __builtin_amdgcn_mfma_f32_16x16x32_bf16(av[kb], bv, acc[ns], 0, 0, 0);
    }
  }

#pragma unroll
  for (int ns = 0; ns < 4; ns++) {
    int nl = ns * 16 + l15;
    int gn = bn + nl;
    if (gn < N3) {
      float vtv = vtS[nl];
#pragma unroll
      for (int reg = 0; reg < 4; reg++) {
        int ml = w * 16 + quad * 4 + reg;
        vposed[(size_t)(bm + ml) * N3 + gn] = acc[ns][reg] + vtv;
      }
    }
  }
}

// ---------------------------------------------------------------------------
// Kernel 4: LBS blend via MFMA, v3 — transposed MFMA, zero LDS round-trip.
// ---------------------------------------------------------------------------
__global__ __launch_bounds__(256) void blend_mfma(
    const ushort* __restrict__ wbf, const ushort* __restrict__ Abf,
    float* __restrict__ out_v) {
  __shared__ __align__(16) ushort Ws[64 * 40];          // 5 KB
  __shared__ __align__(16) ushort Bs[16 * 480 + 160];   // 15.3 KB (+pad)
  const int tid = threadIdx.x;
  const int lane = tid & 63, wv = tid >> 6;
  const int quad = lane >> 4, l15 = lane & 15;
  const int v0 = blockIdx.x * 64;
  const int b0 = blockIdx.y * 16;

  {
    const uint4* srcW = (const uint4*)(wbf + (size_t)v0 * 40);
    uint4* dstW = (uint4*)Ws;
    dstW[tid] = srcW[tid];
    if (tid < 64) dstW[256 + tid] = srcW[256 + tid];
    const uint4* srcB = (const uint4*)(Abf + (size_t)b0 * 480);
    uint4* dstB = (uint4*)Bs;
#pragma unroll
    for (int r = 0; r < 3; r++) dstB[tid + r * 256] = srcB[tid + r * 256];
    if (tid < 192) dstB[768 + tid] = srcB[768 + tid];
    if (tid < 20) dstB[960 + tid] = make_uint4(0u, 0u, 0u, 0u);
  }
  __syncthreads();

  // B-operand: W fragment, col = l15 -> vertex wv*16+l15, k = quad*8..+7
  const short8v wf = *(const short8v*)&Ws[(wv * 16 + l15) * 40 + quad * 8];

  const int gv = v0 + wv * 16 + l15;
  const bool active = (quad < 3) && (gv < VNUM);
  const size_t vbase = (size_t)gv * 3;

  float px[4], py[4], pz[4];
#pragma unroll
  for (int i = 0; i < 4; i++) {
    if (active) {
      const float* p = out_v + (size_t)(b0 + i) * N3 + vbase;
      px[i] = p[0]; py[i] = p[1]; pz[i] = p[2];
    }
  }

#pragma unroll
  for (int b = 0; b < 16; b++) {
    const int slot = b & 3;   // compile-time after full unroll
    short8v afrag = *(const short8v*)&Bs[b * 480 + l15 * 40 + quad * 8];
    floatx4 acc = {0.0f, 0.0f, 0.0f, 0.0f};
    acc = __builtin_amdgcn_mfma_f32_16x16x32_bf16(afrag, wf, acc, 0, 0, 0);
    if (active) {
      out_v[(size_t)(b0 + b) * N3 + vbase + quad] =
          acc[0] * px[slot] + acc[1] * py[slot] + acc[2] * pz[slot] + acc[3];
      if (b < 12) {
        const float* p = out_v + (size_t)(b0 + b + 4) * N3 + vbase;
        px[slot] = p[0]; py[slot] = p[1]; pz[slot] = p[2];
      }
    }
  }
}

extern "C" void kernel_launch(void* const* d_in, const int* in_sizes, int n_in,
                              void* d_out, int out_size, void* d_ws, size_t ws_size,
                              hipStream_t stream) {
  const float* body_pose     = (const float*)d_in[0];
  const float* betas         = (const float*)d_in[1];
  const float* global_orient = (const float*)d_in[2];
  const float* v_template    = (const float*)d_in[3];
  const float* shapedirs     = (const float*)d_in[4];
  const float* posedirs      = (const float*)d_in[5];
  const float* J_regressor   = (const float*)d_in[6];
  const float* lbs_weights   = (const float*)d_in[7];

  float* out = (float*)d_out;
  float* out_v  = out + OUT_V;
  float* out_jt = out + OUT_JT;
  float* out_j  = out + OUT_J;
  float* out_rm = out + OUT_RM;

  float* ws = (float*)d_ws;
  float* JvJs = ws + WS_JVJS;
  ushort* Abf = (ushort*)(ws + WS_ABF);
  ushort* wbf = (ushort*)(ws + WS_WBF);
  ushort* pfb = (ushort*)(ws + WS_PFB);
  ushort* pdT = (ushort*)(ws + WS_PDT);

  hipMemsetAsync(JvJs, 0, KJ * 33 * sizeof(float), stream);
  jreg_kernel<<<dim3(KJ, 4), 256, 0, stream>>>(J_regressor, v_template, shapedirs, JvJs);
  transpose_pd<<<dim3(323, 7), 256, 0, stream>>>(posedirs, pdT, shapedirs,
                                                 lbs_weights, wbf);
  batch_prep<<<BATCH, 64, 0, stream>>>(body_pose, betas, global_orient, JvJs,
                                       out_jt, out_j, out_rm, pfb, Abf);
  vposed_mfma<<<dim3(16, 323), 256, 0, stream>>>(pfb, pdT, v_template, out_v);
  blend_mfma<<<dim3(108, 64), 256, 0, stream>>>(wbf, Abf, out_v);
}